// Round 1
// baseline (15444.095 us; speedup 1.0000x reference)
//
#include <hip/hip_runtime.h>
#include <hip/hip_bf16.h>

// Problem constants
#define B_   32
#define S_   2048
#define I_   256
#define H_   256
#define NWG  16      // workgroups in the persistent kernel (one barrier group)
#define NT   256     // threads per WG
#define UPW  16      // hidden units owned per WG (x4 gates = 64 columns)

typedef __attribute__((ext_vector_type(8))) short short8;   // 8 x bf16 MFMA frag
typedef __attribute__((ext_vector_type(4))) float f32x4;

__device__ __forceinline__ unsigned short f2bf(float f) {
  unsigned u = __builtin_bit_cast(unsigned, f);
  return (unsigned short)((u + 0x7FFFu + ((u >> 16) & 1u)) >> 16);  // RNE
}
__device__ __forceinline__ float bf2f(unsigned short b) {
  unsigned u = ((unsigned)b) << 16;
  return __builtin_bit_cast(float, u);
}

// Pack h0 (fp32) -> exchange buffer 0 as (hi|lo<<16) bf16 pairs, layout [b][u]
__global__ void pack_h0_kernel(const float* __restrict__ h0, unsigned* __restrict__ hex) {
  int idx = blockIdx.x * 256 + threadIdx.x;       // 0..8191
  float v = h0[idx];
  unsigned short hi = f2bf(v);
  unsigned short lo = f2bf(v - bf2f(hi));
  hex[idx] = (unsigned)hi | ((unsigned)lo << 16);
}

// Persistent LSTM kernel. 16 WGs, each owns 16 hidden units across all 4 gates.
// Per step: z_pre = x_t@Wx + h@Wh + b (MFMA, bf16 hi/lo on h-path), z = tanh,
// gates+c/h update WG-locally, h broadcast via LLC with a device-scope barrier.
__global__ __launch_bounds__(NT, 1) void lstm_persist(
    const float* __restrict__ x, const float* __restrict__ c0,
    const float* __restrict__ W, const float* __restrict__ bias,
    float* __restrict__ out, unsigned* __restrict__ flag,
    unsigned* __restrict__ hex) {

  // LDS: h exchange staging (packed hi/lo), x_t staging (bf16), z scratch
  __shared__ unsigned hlds[32 * 260];         // 33,280 B  (pad 260 -> 2-way banks)
  __shared__ unsigned short xlds[32 * 264];   // 16,896 B
  __shared__ float zbuf[32 * 68];             //  8,704 B   (total 58,880 < 64 KB)

  const int tid  = threadIdx.x;
  const int wg   = blockIdx.x;
  const int lane = tid & 63;
  const int wv   = tid >> 6;
  const int mt   = wv & 1;              // m-tile (batches 0-15 / 16-31)
  const int ct0  = (wv >> 1) * 2;       // this wave's two gate tiles: ct0, ct0+1
  const int q    = lane >> 4;           // quad
  const int mm   = lane & 15;           // row-in-tile (A) / col-in-tile (B)

  // ---- one-time: W fragments into registers (B-operand order) ----
  // Wx: single bf16; Wh: hi/lo bf16 pair (3-pass -> near-fp32 recurrent matmul)
  short8 wx[2][8], whh[2][8], whl[2][8];
  #pragma unroll
  for (int c = 0; c < 2; ++c) {
    const int col = (ct0 + c) * 256 + wg * UPW + mm;   // global column (gate*256+unit)
    #pragma unroll
    for (int kc = 0; kc < 8; ++kc) {
      short8 vx, vhh, vhl;
      #pragma unroll
      for (int j = 0; j < 8; ++j) {
        int k = kc * 32 + q * 8 + j;
        float wxv = W[(long)k * 1024 + col];            // rows 0..255 = x part
        float whv = W[(long)(256 + k) * 1024 + col];    // rows 256..511 = h part
        unsigned short xh = f2bf(wxv);
        unsigned short hh = f2bf(whv);
        unsigned short hl = f2bf(whv - bf2f(hh));
        vx[j] = (short)xh; vhh[j] = (short)hh; vhl[j] = (short)hl;
      }
      wx[c][kc] = vx; whh[c][kc] = vhh; whl[c][kc] = vhl;
    }
  }
  float bia[2];
  #pragma unroll
  for (int c = 0; c < 2; ++c) bia[c] = bias[(ct0 + c) * 256 + wg * UPW + mm];

  // ---- combine-phase persistent cell state: pairs p=tid, tid+256 -> (b=p>>4, u=p&15)
  float cst[2];
  #pragma unroll
  for (int r = 0; r < 2; ++r) {
    int p = tid + r * 256;
    cst[r] = c0[(p >> 4) * 256 + wg * UPW + (p & 15)];
  }

  // ---- x prefetch (thread-linear): thread covers x[b=tid>>3][t][i0..i0+32)
  const float* xbase = x + (long)(tid >> 3) * S_ * I_ + (tid & 7) * 32;
  f32x4 xpre[8];
  #pragma unroll
  for (int k = 0; k < 8; ++k) xpre[k] = *(const f32x4*)(xbase + k * 4);

  unsigned* const hex0 = hex;
  unsigned* const hex1 = hex + 8192;

  for (int t = 0; t < S_; ++t) {
    unsigned* const hsrc = (t & 1) ? hex1 : hex0;
    unsigned* const hdst = (t & 1) ? hex0 : hex1;

    // -- stage x_t (prefetched fp32 regs -> bf16 LDS) --
    {
      const int xb = tid >> 3, xi0 = (tid & 7) * 32;
      #pragma unroll
      for (int k = 0; k < 4; ++k) {
        unsigned short u8[8];
        #pragma unroll
        for (int j = 0; j < 4; ++j) {
          u8[j]     = f2bf(xpre[2 * k][j]);
          u8[4 + j] = f2bf(xpre[2 * k + 1][j]);
        }
        *(uint4*)&xlds[xb * 264 + xi0 + k * 8] = *(const uint4*)u8;
      }
    }
    // -- stage h: global exchange -> LDS (plain dwordx4; caches invalidated by barrier acquire)
    #pragma unroll
    for (int k = 0; k < 8; ++k) {
      uint4 v = *(const uint4*)(hsrc + k * 1024 + tid * 4);
      int b = k * 4 + (tid >> 6);
      int col = (tid & 63) * 4;
      *(uint4*)&hlds[b * 260 + col] = v;
    }
    // -- prefetch x for t+1 (independent of recurrence; hidden behind compute/barrier)
    {
      int tn = (t + 1 < S_) ? (t + 1) : t;
      #pragma unroll
      for (int k = 0; k < 8; ++k) xpre[k] = *(const f32x4*)(xbase + (long)tn * I_ + k * 4);
    }
    __syncthreads();

    // -- MFMA phase: z_pre tiles (16x16), K=256 in 8 chunks, 3 passes on h path --
    f32x4 accX[2], accH[2], accM[2];
    #pragma unroll
    for (int c = 0; c < 2; ++c) {
      accX[c] = (f32x4){0.f, 0.f, 0.f, 0.f};
      accH[c] = (f32x4){0.f, 0.f, 0.f, 0.f};
      accM[c] = (f32x4){0.f, 0.f, 0.f, 0.f};
    }
    const int arow = mm + 16 * mt;
    #pragma unroll
    for (int kc = 0; kc < 8; ++kc) {
      short8 ax = *(const short8*)&xlds[arow * 264 + kc * 32 + q * 8];
      uint4 p0 = *(const uint4*)&hlds[arow * 260 + kc * 32 + q * 8];
      uint4 p1 = *(const uint4*)&hlds[arow * 260 + kc * 32 + q * 8 + 4];
      unsigned pu[8] = {p0.x, p0.y, p0.z, p0.w, p1.x, p1.y, p1.z, p1.w};
      short8 ahh, ahl;
      #pragma unroll
      for (int j = 0; j < 8; ++j) {
        ahh[j] = (short)(pu[j] & 0xffffu);
        ahl[j] = (short)(pu[j] >> 16);
      }
      #pragma unroll
      for (int c = 0; c < 2; ++c) {
        accX[c] = __builtin_amdgcn_mfma_f32_16x16x32_bf16(ax,  wx[c][kc],  accX[c], 0, 0, 0);
        accH[c] = __builtin_amdgcn_mfma_f32_16x16x32_bf16(ahh, whh[c][kc], accH[c], 0, 0, 0);
        accM[c] = __builtin_amdgcn_mfma_f32_16x16x32_bf16(ahh, whl[c][kc], accM[c], 0, 0, 0);
        accM[c] = __builtin_amdgcn_mfma_f32_16x16x32_bf16(ahl, whh[c][kc], accM[c], 0, 0, 0);
      }
    }
    // epilogue: z = tanh(z_pre + b), scatter to zbuf (C/D layout: row=q*4+r, col=mm)
    #pragma unroll
    for (int c = 0; c < 2; ++c) {
      #pragma unroll
      for (int r = 0; r < 4; ++r) {
        float zp = accX[c][r] + accH[c][r] + accM[c][r] + bia[c];
        int brow = q * 4 + r + 16 * mt;
        zbuf[brow * 68 + (ct0 + c) * 16 + mm] = tanhf(zp);
      }
    }
    __syncthreads();

    // -- combine: gates, cell/hidden update, write out + exchange --
    #pragma unroll
    for (int r = 0; r < 2; ++r) {
      int p = tid + r * 256;
      int u = p & 15, b = p >> 4;
      float zi = zbuf[b * 68 +  0 + u];
      float zf = zbuf[b * 68 + 16 + u];
      float zg = zbuf[b * 68 + 32 + u];
      float zo = zbuf[b * 68 + 48 + u];
      float ig = 1.f / (1.f + __expf(-zi));
      float fg = 1.f / (1.f + __expf(-zf));
      float gg = tanhf(zg);
      float og = 1.f / (1.f + __expf(-zo));
      float cn = fg * cst[r] + ig * gg;
      cst[r] = cn;
      float hn = tanhf(cn) * og;
      out[((long)b * S_ + t) * H_ + wg * UPW + u] = hn;
      unsigned short hhi = f2bf(hn);
      unsigned short hlo = f2bf(hn - bf2f(hhi));
      unsigned hp = (unsigned)hhi | ((unsigned)hlo << 16);
      __hip_atomic_store(hdst + b * 256 + wg * UPW + u, hp,
                         __ATOMIC_RELAXED, __HIP_MEMORY_SCOPE_AGENT);
    }

    // -- device-scope barrier across the 16 WGs --
    __builtin_amdgcn_fence(__ATOMIC_RELEASE, "agent");
    __syncthreads();   // compiler drains vmcnt before s_barrier -> all stores globally visible
    if (tid == 0) {
      __hip_atomic_fetch_add(flag, 1u, __ATOMIC_RELEASE, __HIP_MEMORY_SCOPE_AGENT);
      unsigned target = (unsigned)(NWG * (t + 1));
      while (__hip_atomic_load(flag, __ATOMIC_RELAXED, __HIP_MEMORY_SCOPE_AGENT) < target)
        __builtin_amdgcn_s_sleep(1);
      __builtin_amdgcn_fence(__ATOMIC_ACQUIRE, "agent");  // invalidate L1 + XCD L2
    }
    __syncthreads();
  }
}

extern "C" void kernel_launch(void* const* d_in, const int* in_sizes, int n_in,
                              void* d_out, int out_size, void* d_ws, size_t ws_size,
                              hipStream_t stream) {
  const float* x    = (const float*)d_in[0];
  const float* h0   = (const float*)d_in[1];
  const float* c0   = (const float*)d_in[2];
  const float* W    = (const float*)d_in[3];
  const float* bias = (const float*)d_in[4];
  float* out = (float*)d_out;

  // workspace: [0,128) barrier flag, [256, 256+64K) h exchange (2 buffers)
  unsigned* flag = (unsigned*)d_ws;
  unsigned* hex  = (unsigned*)((char*)d_ws + 256);

  // outputs 1 and 2 of the reference are zeros: clear tail of d_out
  hipMemsetAsync((char*)d_out + (size_t)B_ * S_ * H_ * 4, 0, 2 * B_ * H_ * 4, stream);
  // reset barrier counter every launch (re-poisoned to 0xAA by harness)
  hipMemsetAsync(d_ws, 0, 256, stream);

  pack_h0_kernel<<<32, 256, 0, stream>>>(h0, hex);
  lstm_persist<<<NWG, NT, 0, stream>>>(x, c0, W, bias, out, flag, hex);
}

// Round 2
// 9350.986 us; speedup vs baseline: 1.6516x; 1.6516x over previous
//
#include <hip/hip_runtime.h>
#include <hip/hip_bf16.h>

// Problem constants
#define B_   32
#define S_   2048
#define I_   256
#define H_   256
#define NWG  16      // workgroups in the persistent kernel (one barrier group)
#define NT   256     // threads per WG
#define UPW  16      // hidden units owned per WG (x4 gates = 64 columns)

typedef __attribute__((ext_vector_type(8))) short short8;   // 8 x bf16 MFMA frag
typedef __attribute__((ext_vector_type(4))) float f32x4;

__device__ __forceinline__ unsigned short f2bf(float f) {
  unsigned u = __builtin_bit_cast(unsigned, f);
  return (unsigned short)((u + 0x7FFFu + ((u >> 16) & 1u)) >> 16);  // RNE
}
__device__ __forceinline__ float bf2f(unsigned short b) {
  unsigned u = ((unsigned)b) << 16;
  return __builtin_bit_cast(float, u);
}

// Pack h0 (fp32) -> exchange buffer 0 as (hi|lo<<16) bf16 pairs, layout [b][u]
__global__ void pack_h0_kernel(const float* __restrict__ h0, unsigned* __restrict__ hex) {
  int idx = blockIdx.x * 256 + threadIdx.x;       // 0..8191
  float v = h0[idx];
  unsigned short hi = f2bf(v);
  unsigned short lo = f2bf(v - bf2f(hi));
  hex[idx] = (unsigned)hi | ((unsigned)lo << 16);
}

// Persistent LSTM kernel. 16 WGs, each owns 16 hidden units across all 4 gates.
// Sync protocol (fence-free): h exchange + flags live at LLC via sc0/sc1
// (agent-scope relaxed atomics). Release = drain vmcnt + s_barrier + per-WG
// flag store (own cacheline). Acquire = per-wave poll of all 16 flags.
// No L2 writeback/invalidate ops anywhere in the loop.
__global__ __launch_bounds__(NT, 1) void lstm_persist(
    const float* __restrict__ x, const float* __restrict__ c0,
    const float* __restrict__ W, const float* __restrict__ bias,
    float* __restrict__ out, unsigned* __restrict__ flag,
    unsigned* __restrict__ hex) {

  // LDS: h exchange staging (packed hi/lo), x_t staging (bf16), z scratch
  __shared__ unsigned hlds[32 * 260];         // 33,280 B  (pad 260 -> 2-way banks)
  __shared__ unsigned short xlds[32 * 264];   // 16,896 B
  __shared__ float zbuf[32 * 68];             //  8,704 B   (total 58,880 < 64 KB)

  const int tid  = threadIdx.x;
  const int wg   = blockIdx.x;
  const int lane = tid & 63;
  const int wv   = tid >> 6;
  const int mt   = wv & 1;              // m-tile (batches 0-15 / 16-31)
  const int ct0  = (wv >> 1) * 2;       // this wave's two gate tiles: ct0, ct0+1
  const int q    = lane >> 4;           // quad
  const int mm   = lane & 15;           // row-in-tile (A) / col-in-tile (B)

  // ---- one-time: W fragments into registers (B-operand order) ----
  // Wx: single bf16; Wh: hi/lo bf16 pair (3-pass -> near-fp32 recurrent matmul)
  short8 wx[2][8], whh[2][8], whl[2][8];
  #pragma unroll
  for (int c = 0; c < 2; ++c) {
    const int col = (ct0 + c) * 256 + wg * UPW + mm;   // global column (gate*256+unit)
    #pragma unroll
    for (int kc = 0; kc < 8; ++kc) {
      short8 vx, vhh, vhl;
      #pragma unroll
      for (int j = 0; j < 8; ++j) {
        int k = kc * 32 + q * 8 + j;
        float wxv = W[(long)k * 1024 + col];            // rows 0..255 = x part
        float whv = W[(long)(256 + k) * 1024 + col];    // rows 256..511 = h part
        unsigned short xh = f2bf(wxv);
        unsigned short hh = f2bf(whv);
        unsigned short hl = f2bf(whv - bf2f(hh));
        vx[j] = (short)xh; vhh[j] = (short)hh; vhl[j] = (short)hl;
      }
      wx[c][kc] = vx; whh[c][kc] = vhh; whl[c][kc] = vhl;
    }
  }
  float bia[2];
  #pragma unroll
  for (int c = 0; c < 2; ++c) bia[c] = bias[(ct0 + c) * 256 + wg * UPW + mm];

  // ---- combine-phase indexing: thread owns batch cb, unit pair (cu0, cu0+1)
  const int cb  = tid >> 3;             // 0..31
  const int cu0 = (tid & 7) * 2;        // 0,2,..,14
  float cst[2];
  cst[0] = c0[cb * 256 + wg * UPW + cu0];
  cst[1] = c0[cb * 256 + wg * UPW + cu0 + 1];

  // ---- x prefetch (thread-linear): thread covers x[b=tid>>3][t][i0..i0+32)
  const float* xbase = x + (long)(tid >> 3) * S_ * I_ + (tid & 7) * 32;
  f32x4 xpre[8];
  #pragma unroll
  for (int k = 0; k < 8; ++k) xpre[k] = *(const f32x4*)(xbase + k * 4);

  unsigned* const hex0 = hex;
  unsigned* const hex1 = hex + 8192;

  for (int t = 0; t < S_; ++t) {
    unsigned* const hsrc = (t & 1) ? hex1 : hex0;
    unsigned* const hdst = (t & 1) ? hex0 : hex1;

    // -- acquire: every wave polls all 16 per-WG flags (own cachelines) --
    if (t > 0) {
      const unsigned* fp = flag + (lane & 15) * 32;   // 128B stride per flag
      const unsigned tgt = (unsigned)t;
      while (true) {
        unsigned v = __hip_atomic_load(fp, __ATOMIC_RELAXED, __HIP_MEMORY_SCOPE_AGENT);
        if (__ballot(v >= tgt) == ~0ull) break;       // lanes>=16 mirror lanes 0..15
        __builtin_amdgcn_s_sleep(1);
      }
      asm volatile("" ::: "memory");   // compiler barrier: keep h loads below the poll
    }

    // -- issue h loads early (LLC-bypass 8B atomics); latency overlaps x staging --
    unsigned long long hv[16];
    const unsigned long long* hsrc8 = (const unsigned long long*)hsrc;
    #pragma unroll
    for (int k = 0; k < 16; ++k)
      hv[k] = __hip_atomic_load(hsrc8 + k * 256 + tid, __ATOMIC_RELAXED,
                                __HIP_MEMORY_SCOPE_AGENT);

    // -- stage x_t (prefetched fp32 regs -> bf16 LDS) --
    {
      const int xb = tid >> 3, xi0 = (tid & 7) * 32;
      #pragma unroll
      for (int k = 0; k < 4; ++k) {
        unsigned short u8[8];
        #pragma unroll
        for (int j = 0; j < 4; ++j) {
          u8[j]     = f2bf(xpre[2 * k][j]);
          u8[4 + j] = f2bf(xpre[2 * k + 1][j]);
        }
        *(uint4*)&xlds[xb * 264 + xi0 + k * 8] = *(const uint4*)u8;
      }
    }
    // -- prefetch x for t+1 (independent of recurrence) --
    {
      int tn = (t + 1 < S_) ? (t + 1) : t;
      #pragma unroll
      for (int k = 0; k < 8; ++k) xpre[k] = *(const f32x4*)(xbase + (long)tn * I_ + k * 4);
    }
    // -- h regs -> LDS (compiler inserts vmcnt waits on hv use) --
    #pragma unroll
    for (int k = 0; k < 16; ++k) {
      int b  = k * 2 + (tid >> 7);
      int u0 = (tid & 127) * 2;
      *(unsigned long long*)&hlds[b * 260 + u0] = hv[k];
    }
    __syncthreads();

    // -- MFMA phase: z_pre tiles (16x16), K=256 in 8 chunks, 3 passes on h path --
    f32x4 accX[2], accH[2], accM[2];
    #pragma unroll
    for (int c = 0; c < 2; ++c) {
      accX[c] = (f32x4){0.f, 0.f, 0.f, 0.f};
      accH[c] = (f32x4){0.f, 0.f, 0.f, 0.f};
      accM[c] = (f32x4){0.f, 0.f, 0.f, 0.f};
    }
    const int arow = mm + 16 * mt;
    #pragma unroll
    for (int kc = 0; kc < 8; ++kc) {
      short8 ax = *(const short8*)&xlds[arow * 264 + kc * 32 + q * 8];
      uint4 p0 = *(const uint4*)&hlds[arow * 260 + kc * 32 + q * 8];
      uint4 p1 = *(const uint4*)&hlds[arow * 260 + kc * 32 + q * 8 + 4];
      unsigned pu[8] = {p0.x, p0.y, p0.z, p0.w, p1.x, p1.y, p1.z, p1.w};
      short8 ahh, ahl;
      #pragma unroll
      for (int j = 0; j < 8; ++j) {
        ahh[j] = (short)(pu[j] & 0xffffu);
        ahl[j] = (short)(pu[j] >> 16);
      }
      #pragma unroll
      for (int c = 0; c < 2; ++c) {
        accX[c] = __builtin_amdgcn_mfma_f32_16x16x32_bf16(ax,  wx[c][kc],  accX[c], 0, 0, 0);
        accH[c] = __builtin_amdgcn_mfma_f32_16x16x32_bf16(ahh, whh[c][kc], accH[c], 0, 0, 0);
        accM[c] = __builtin_amdgcn_mfma_f32_16x16x32_bf16(ahh, whl[c][kc], accM[c], 0, 0, 0);
        accM[c] = __builtin_amdgcn_mfma_f32_16x16x32_bf16(ahl, whh[c][kc], accM[c], 0, 0, 0);
      }
    }
    // epilogue: z = tanh(z_pre + b), scatter to zbuf (C/D layout: row=q*4+r, col=mm)
    #pragma unroll
    for (int c = 0; c < 2; ++c) {
      #pragma unroll
      for (int r = 0; r < 4; ++r) {
        float zp = accX[c][r] + accH[c][r] + accM[c][r] + bia[c];
        int brow = q * 4 + r + 16 * mt;
        zbuf[brow * 68 + (ct0 + c) * 16 + mm] = tanhf(zp);
      }
    }
    __syncthreads();

    // -- combine: gates, cell/hidden update for units (cu0, cu0+1) of batch cb --
    float hn2[2];
    #pragma unroll
    for (int j = 0; j < 2; ++j) {
      int u = cu0 + j;
      float zi = zbuf[cb * 68 +  0 + u];
      float zf = zbuf[cb * 68 + 16 + u];
      float zg = zbuf[cb * 68 + 32 + u];
      float zo = zbuf[cb * 68 + 48 + u];
      float ig = 1.f / (1.f + __expf(-zi));
      float fg = 1.f / (1.f + __expf(-zf));
      float gg = tanhf(zg);
      float og = 1.f / (1.f + __expf(-zo));
      float cn = fg * cst[j] + ig * gg;
      cst[j] = cn;
      hn2[j] = tanhf(cn) * og;
    }
    // out: plain 8B store (dirty in local L2; kernel-end release writes back)
    *(float2*)(out + ((long)cb * S_ + t) * H_ + wg * UPW + cu0) =
        make_float2(hn2[0], hn2[1]);
    // h exchange: one 8B write-through (LLC) store
    {
      unsigned short h0h = f2bf(hn2[0]);
      unsigned short h0l = f2bf(hn2[0] - bf2f(h0h));
      unsigned short h1h = f2bf(hn2[1]);
      unsigned short h1l = f2bf(hn2[1] - bf2f(h1h));
      unsigned p0 = (unsigned)h0h | ((unsigned)h0l << 16);
      unsigned p1 = (unsigned)h1h | ((unsigned)h1l << 16);
      unsigned long long hp = (unsigned long long)p0 | ((unsigned long long)p1 << 32);
      __hip_atomic_store((unsigned long long*)(hdst + cb * 256 + wg * UPW + cu0), hp,
                         __ATOMIC_RELAXED, __HIP_MEMORY_SCOPE_AGENT);
    }

    // -- release: every wave drains its stores, barrier, then tid0 publishes --
    asm volatile("s_waitcnt vmcnt(0)" ::: "memory");
    __syncthreads();
    if (tid == 0)
      __hip_atomic_store(flag + wg * 32, (unsigned)(t + 1), __ATOMIC_RELAXED,
                         __HIP_MEMORY_SCOPE_AGENT);
  }
}

extern "C" void kernel_launch(void* const* d_in, const int* in_sizes, int n_in,
                              void* d_out, int out_size, void* d_ws, size_t ws_size,
                              hipStream_t stream) {
  const float* x    = (const float*)d_in[0];
  const float* h0   = (const float*)d_in[1];
  const float* c0   = (const float*)d_in[2];
  const float* W    = (const float*)d_in[3];
  const float* bias = (const float*)d_in[4];
  float* out = (float*)d_out;

  // workspace: [0, 4096) per-WG flags (128B stride), [4096, 4096+64K) h exchange
  unsigned* flag = (unsigned*)d_ws;
  unsigned* hex  = (unsigned*)((char*)d_ws + 4096);

  // outputs 1 and 2 of the reference are zeros: clear tail of d_out
  hipMemsetAsync((char*)d_out + (size_t)B_ * S_ * H_ * 4, 0, 2 * B_ * H_ * 4, stream);
  // reset flags every launch (harness re-poisons d_ws to 0xAA)
  hipMemsetAsync(d_ws, 0, 4096, stream);

  pack_h0_kernel<<<32, 256, 0, stream>>>(h0, hex);
  lstm_persist<<<NWG, NT, 0, stream>>>(x, c0, W, bias, out, flag, hex);
}

// Round 3
// 7997.115 us; speedup vs baseline: 1.9312x; 1.1693x over previous
//
#include <hip/hip_runtime.h>
#include <hip/hip_bf16.h>

// Problem constants
#define B_   32
#define S_   2048
#define I_   256
#define H_   256
#define NWG  16      // workgroups in the persistent kernel
#define NT   256     // threads per WG
#define UPW  16      // hidden units owned per WG (x4 gates = 64 columns)
#define TC   16      // timesteps per precompute WG

typedef __attribute__((ext_vector_type(8))) short short8;   // 8 x bf16 MFMA frag
typedef __attribute__((ext_vector_type(4))) float f32x4;
typedef unsigned long long u64;

__device__ __forceinline__ unsigned short f2bf(float f) {
  unsigned u = __builtin_bit_cast(unsigned, f);
  return (unsigned short)((u + 0x7FFFu + ((u >> 16) & 1u)) >> 16);  // RNE
}
__device__ __forceinline__ float bf2f(unsigned short b) {
  unsigned u = ((unsigned)b) << 16;
  return __builtin_bit_cast(float, u);
}
__device__ __forceinline__ float fast_rcp(float x) { return __builtin_amdgcn_rcpf(x); }
// |inputs| are bounded (<~8) in this net: no overflow concerns.
__device__ __forceinline__ float fast_tanh(float x) {
  return 1.f - 2.f * fast_rcp(__expf(2.f * x) + 1.f);
}
__device__ __forceinline__ float fast_sig(float x) {
  return fast_rcp(1.f + __expf(-x));
}

// Pack h0 -> exchange buffer 0. Word w covers units (2u,2u+1) of batch b:
// low dword = (hi0 | hi1<<16), high dword = (lo0 | lo1<<16), tag = bit32 (lo0 LSB).
// tag(t=0) = 0.
__global__ void pack_h0_kernel(const float* __restrict__ h0, u64* __restrict__ hex) {
  int idx = blockIdx.x * 256 + threadIdx.x;       // 0..4095
  float v0 = h0[idx * 2], v1 = h0[idx * 2 + 1];
  unsigned short h0h = f2bf(v0);
  unsigned short h0l = f2bf(v0 - bf2f(h0h));
  unsigned short h1h = f2bf(v1);
  unsigned short h1l = f2bf(v1 - bf2f(h1h));
  unsigned hiw = (unsigned)h0h | ((unsigned)h1h << 16);
  unsigned low = ((unsigned)h0l & 0xFFFEu) | ((unsigned)h1l << 16);  // tag=0
  hex[idx] = (u64)hiw | ((u64)low << 32);
}

// Full-chip precompute of zx = x@Wx + bias, stored in MFMA C-layout so the
// persistent kernel streams it with 2 coalesced 16B loads/thread/step.
// Grid: (S/TC) tchunks x 16 unit-groups.
__global__ __launch_bounds__(NT) void zx_precompute(
    const float* __restrict__ x, const float* __restrict__ W,
    const float* __restrict__ bias, float* __restrict__ zx) {
  __shared__ unsigned short xlds[32 * 264];

  const int tid  = threadIdx.x;
  const int ug   = blockIdx.x & 15;
  const int tc   = blockIdx.x >> 4;
  const int lane = tid & 63;
  const int wv   = tid >> 6;
  const int mt   = wv & 1;
  const int ct0  = (wv >> 1) * 2;
  const int q    = lane >> 4;
  const int mm   = lane & 15;

  short8 wx[2][8];
  float  bia[2];
  #pragma unroll
  for (int c = 0; c < 2; ++c) {
    const int col = (ct0 + c) * 256 + ug * UPW + mm;
    #pragma unroll
    for (int kc = 0; kc < 8; ++kc) {
      short8 v;
      #pragma unroll
      for (int j = 0; j < 8; ++j) {
        int k = kc * 32 + q * 8 + j;
        v[j] = (short)f2bf(W[(long)k * 1024 + col]);   // rows 0..255 = x part
      }
      wx[c][kc] = v;
    }
    bia[c] = bias[(ct0 + c) * 256 + ug * UPW + mm];
  }

  for (int tt = 0; tt < TC; ++tt) {
    const int t = tc * TC + tt;
    // stage x_t as bf16 into LDS
    const int xb = tid >> 3, xi0 = (tid & 7) * 32;
    const float* xp = x + ((long)xb * S_ + t) * I_ + xi0;
    #pragma unroll
    for (int k2 = 0; k2 < 4; ++k2) {
      f32x4 a  = *(const f32x4*)(xp + k2 * 8);
      f32x4 b2 = *(const f32x4*)(xp + k2 * 8 + 4);
      unsigned short u8[8];
      #pragma unroll
      for (int j = 0; j < 4; ++j) { u8[j] = f2bf(a[j]); u8[4 + j] = f2bf(b2[j]); }
      *(uint4*)&xlds[xb * 264 + xi0 + k2 * 8] = *(const uint4*)u8;
    }
    __syncthreads();
    f32x4 acc[2];
    acc[0] = (f32x4){0.f, 0.f, 0.f, 0.f};
    acc[1] = (f32x4){0.f, 0.f, 0.f, 0.f};
    const int arow = mm + 16 * mt;
    #pragma unroll
    for (int kc = 0; kc < 8; ++kc) {
      short8 ax = *(const short8*)&xlds[arow * 264 + kc * 32 + q * 8];
      acc[0] = __builtin_amdgcn_mfma_f32_16x16x32_bf16(ax, wx[0][kc], acc[0], 0, 0, 0);
      acc[1] = __builtin_amdgcn_mfma_f32_16x16x32_bf16(ax, wx[1][kc], acc[1], 0, 0, 0);
    }
    float* zp = zx + (((long)t * 16 + ug) * 256 + tid) * 8;
    f32x4 s0, s1;
    #pragma unroll
    for (int r = 0; r < 4; ++r) { s0[r] = acc[0][r] + bia[0]; s1[r] = acc[1][r] + bia[1]; }
    *(f32x4*)zp = s0;
    *(f32x4*)(zp + 4) = s1;
    __syncthreads();   // protect xlds before next stage
  }
}

// Persistent LSTM. Tag-in-data exchange: no flags, no fences, no vmcnt drains.
// Word validity = (bit32 == (t>>1)&1). 2-buffer hex; skew provably < 4.
template<bool PRE>
__global__ __launch_bounds__(NT, 1) void lstm_persist(
    const float* __restrict__ x, const float* __restrict__ c0,
    const float* __restrict__ W, const float* __restrict__ bias,
    float* __restrict__ out, u64* __restrict__ hex,
    const float* __restrict__ zx) {

  __shared__ unsigned short hh_lds[32 * 264];   // hi plane  16,896 B
  __shared__ unsigned short hl_lds[32 * 264];   // lo plane  16,896 B
  __shared__ float zbuf[32 * 68];               //            8,704 B
  __shared__ unsigned short xlds[PRE ? 1 : 32 * 264];

  const int tid  = threadIdx.x;
  const int wg   = blockIdx.x;
  const int lane = tid & 63;
  const int wv   = tid >> 6;
  const int mt   = wv & 1;
  const int ct0  = (wv >> 1) * 2;
  const int q    = lane >> 4;
  const int mm   = lane & 15;

  // ---- one-time: Wh fragments (hi/lo bf16) into registers; Wx only if !PRE
  short8 whh[2][8], whl[2][8];
  short8 wx[2][8];
  float  bia[2];
  #pragma unroll
  for (int c = 0; c < 2; ++c) {
    const int col = (ct0 + c) * 256 + wg * UPW + mm;
    #pragma unroll
    for (int kc = 0; kc < 8; ++kc) {
      short8 vhh, vhl, vx;
      #pragma unroll
      for (int j = 0; j < 8; ++j) {
        int k = kc * 32 + q * 8 + j;
        float whv = W[(long)(256 + k) * 1024 + col];
        unsigned short hh = f2bf(whv);
        vhh[j] = (short)hh;
        vhl[j] = (short)f2bf(whv - bf2f(hh));
        if constexpr (!PRE) vx[j] = (short)f2bf(W[(long)k * 1024 + col]);
      }
      whh[c][kc] = vhh; whl[c][kc] = vhl;
      if constexpr (!PRE) wx[c][kc] = vx;
    }
    if constexpr (!PRE) bia[c] = bias[(ct0 + c) * 256 + wg * UPW + mm];
  }

  // combine-phase: thread owns batch cb, unit pair (cu0, cu0+1)
  const int cb  = tid >> 3;
  const int cu0 = (tid & 7) * 2;
  float cst[2];
  cst[0] = c0[cb * 256 + wg * UPW + cu0];
  cst[1] = c0[cb * 256 + wg * UPW + cu0 + 1];

  u64* const hex0 = hex;
  u64* const hex1 = hex + 4096;

  // zx pipeline regs
  f32x4 zxv[2], zxn[2];
  if constexpr (PRE) {
    const float* zp = zx + ((long)0 * 16 + wg) * 2048 + tid * 8;
    zxv[0] = *(const f32x4*)zp;
    zxv[1] = *(const f32x4*)(zp + 4);
  }

  for (int t = 0; t < S_; ++t) {
    u64* const hsrc8 = (t & 1) ? hex1 : hex0;
    u64* const hdst8 = (t & 1) ? hex0 : hex1;
    const unsigned tagbit = (unsigned)((t >> 1) & 1);

    // -- prefetch zx for t+1 (independent of recurrence) --
    if constexpr (PRE) {
      int tn = (t + 1 < S_) ? (t + 1) : t;
      const float* zp = zx + ((long)tn * 16 + wg) * 2048 + tid * 8;
      zxn[0] = *(const f32x4*)zp;
      zxn[1] = *(const f32x4*)(zp + 4);
    }

    // -- poll h: blast 16 loads, then retry only stale words --
    u64 hv[16];
    #pragma unroll
    for (int k = 0; k < 16; ++k)
      hv[k] = __hip_atomic_load(hsrc8 + (k << 8) + tid, __ATOMIC_RELAXED,
                                __HIP_MEMORY_SCOPE_AGENT);
    unsigned need = 0;
    #pragma unroll
    for (int k = 0; k < 16; ++k)
      if (((unsigned)(hv[k] >> 32) & 1u) != tagbit) need |= 1u << k;
    while (__ballot(need != 0u) != 0ull) {
      u64 tmp[16];
      #pragma unroll
      for (int k = 0; k < 16; ++k)
        if (need & (1u << k))
          tmp[k] = __hip_atomic_load(hsrc8 + (k << 8) + tid, __ATOMIC_RELAXED,
                                     __HIP_MEMORY_SCOPE_AGENT);
      #pragma unroll
      for (int k = 0; k < 16; ++k)
        if ((need & (1u << k)) && (((unsigned)(tmp[k] >> 32) & 1u) == tagbit)) {
          hv[k] = tmp[k];
          need &= ~(1u << k);
        }
    }

    // -- stage h into split hi/lo LDS planes (no unpack VALU) --
    #pragma unroll
    for (int k = 0; k < 16; ++k) {
      int b  = k * 2 + (tid >> 7);
      int du = (tid & 127);
      *(unsigned*)&hh_lds[b * 264 + du * 2] = (unsigned)hv[k];
      *(unsigned*)&hl_lds[b * 264 + du * 2] = (unsigned)(hv[k] >> 32);
    }
    // -- stage x_t (fallback path only) --
    if constexpr (!PRE) {
      const int xb = tid >> 3, xi0 = (tid & 7) * 32;
      const float* xp = x + ((long)xb * S_ + t) * I_ + xi0;
      #pragma unroll
      for (int k2 = 0; k2 < 4; ++k2) {
        f32x4 a  = *(const f32x4*)(xp + k2 * 8);
        f32x4 b2 = *(const f32x4*)(xp + k2 * 8 + 4);
        unsigned short u8[8];
        #pragma unroll
        for (int j = 0; j < 4; ++j) { u8[j] = f2bf(a[j]); u8[4 + j] = f2bf(b2[j]); }
        *(uint4*)&xlds[xb * 264 + xi0 + k2 * 8] = *(const uint4*)u8;
      }
    }
    __syncthreads();   // SYNC1

    // -- MFMA: accH (hi*hi) + accM (hi*lo + lo*hi), fragments direct from LDS --
    f32x4 accH[2], accM[2], accX[2];
    #pragma unroll
    for (int c = 0; c < 2; ++c) {
      accH[c] = (f32x4){0.f, 0.f, 0.f, 0.f};
      accM[c] = (f32x4){0.f, 0.f, 0.f, 0.f};
      if constexpr (!PRE) accX[c] = (f32x4){0.f, 0.f, 0.f, 0.f};
    }
    const int arow = mm + 16 * mt;
    #pragma unroll
    for (int kc = 0; kc < 8; ++kc) {
      short8 ahh = *(const short8*)&hh_lds[arow * 264 + kc * 32 + q * 8];
      short8 ahl = *(const short8*)&hl_lds[arow * 264 + kc * 32 + q * 8];
      short8 ax;
      if constexpr (!PRE) ax = *(const short8*)&xlds[arow * 264 + kc * 32 + q * 8];
      #pragma unroll
      for (int c = 0; c < 2; ++c) {
        accH[c] = __builtin_amdgcn_mfma_f32_16x16x32_bf16(ahh, whh[c][kc], accH[c], 0, 0, 0);
        accM[c] = __builtin_amdgcn_mfma_f32_16x16x32_bf16(ahh, whl[c][kc], accM[c], 0, 0, 0);
        accM[c] = __builtin_amdgcn_mfma_f32_16x16x32_bf16(ahl, whh[c][kc], accM[c], 0, 0, 0);
        if constexpr (!PRE)
          accX[c] = __builtin_amdgcn_mfma_f32_16x16x32_bf16(ax, wx[c][kc], accX[c], 0, 0, 0);
      }
    }
    // epilogue: z = tanh(zx + h@Wh), C-layout scatter to zbuf
    #pragma unroll
    for (int c = 0; c < 2; ++c) {
      #pragma unroll
      for (int r = 0; r < 4; ++r) {
        float zp = accH[c][r] + accM[c][r];
        if constexpr (PRE) zp += zxv[c][r];
        else               zp += accX[c][r] + bia[c];
        int brow = q * 4 + r + 16 * mt;
        zbuf[brow * 68 + (ct0 + c) * 16 + mm] = fast_tanh(zp);
      }
    }
    __syncthreads();   // SYNC2

    // -- combine: gates, cell/hidden update; publish tagged h word --
    float hn2[2];
    #pragma unroll
    for (int j = 0; j < 2; ++j) {
      int u = cu0 + j;
      float zi = zbuf[cb * 68 +  0 + u];
      float zf = zbuf[cb * 68 + 16 + u];
      float zg = zbuf[cb * 68 + 32 + u];
      float zo = zbuf[cb * 68 + 48 + u];
      float ig = fast_sig(zi);
      float fg = fast_sig(zf);
      float gg = fast_tanh(zg);
      float og = fast_sig(zo);
      float cn = fg * cst[j] + ig * gg;
      cst[j] = cn;
      hn2[j] = fast_tanh(cn) * og;
    }
    *(float2*)(out + ((long)cb * S_ + t) * H_ + wg * UPW + cu0) =
        make_float2(hn2[0], hn2[1]);
    {
      const unsigned tagw = (unsigned)(((t + 1) >> 1) & 1);
      unsigned short h0h = f2bf(hn2[0]);
      unsigned short h0l = f2bf(hn2[0] - bf2f(h0h));
      unsigned short h1h = f2bf(hn2[1]);
      unsigned short h1l = f2bf(hn2[1] - bf2f(h1h));
      unsigned hiw = (unsigned)h0h | ((unsigned)h1h << 16);
      unsigned low = (((unsigned)h0l & 0xFFFEu) | tagw) | ((unsigned)h1l << 16);
      u64 word = (u64)hiw | ((u64)low << 32);
      __hip_atomic_store(hdst8 + cb * 128 + wg * 8 + (cu0 >> 1), word,
                         __ATOMIC_RELAXED, __HIP_MEMORY_SCOPE_AGENT);
    }
    if constexpr (PRE) { zxv[0] = zxn[0]; zxv[1] = zxn[1]; }
  }
}

extern "C" void kernel_launch(void* const* d_in, const int* in_sizes, int n_in,
                              void* d_out, int out_size, void* d_ws, size_t ws_size,
                              hipStream_t stream) {
  const float* x    = (const float*)d_in[0];
  const float* h0   = (const float*)d_in[1];
  const float* c0   = (const float*)d_in[2];
  const float* W    = (const float*)d_in[3];
  const float* bias = (const float*)d_in[4];
  float* out = (float*)d_out;

  // ws layout: [0, 64K) h exchange (2 x 32 KB), [64K, 64K+256M) zx
  u64*   hex = (u64*)d_ws;
  float* zx  = (float*)((char*)d_ws + 65536);
  const size_t zx_bytes = (size_t)S_ * B_ * 4 * H_ * sizeof(float);  // 256 MiB

  // outputs 1 and 2 of the reference are zeros
  hipMemsetAsync((char*)d_out + (size_t)B_ * S_ * H_ * 4, 0, 2 * B_ * H_ * 4, stream);
  // hex buffer 1: all-ones -> tag bit 1, invalid for its first consumer (t=1, tag 0)
  hipMemsetAsync((char*)d_ws + 32768, 0xFF, 32768, stream);

  pack_h0_kernel<<<16, 256, 0, stream>>>(h0, hex);
  if (ws_size >= 65536 + zx_bytes) {
    zx_precompute<<<(S_ / TC) * 16, NT, 0, stream>>>(x, W, bias, zx);
    lstm_persist<true><<<NWG, NT, 0, stream>>>(x, c0, W, bias, out, hex, zx);
  } else {
    lstm_persist<false><<<NWG, NT, 0, stream>>>(x, c0, W, bias, out, hex, nullptr);
  }
}